// Round 3
// baseline (136.823 us; speedup 1.0000x reference)
//
#include <hip/hip_runtime.h>

// Problem constants (from reference): B=4096, I=30000, O=10000, I == 3*O.
#define BATCH 4096
#define INF   30000
#define OUTF  10000
#define GROUPS_PER_ROW (OUTF / 4)     // 2500 float4-groups per output row
#define P_SLICES 512                  // batch parallel slices
#define ROWS_PER_THREAD (BATCH / P_SLICES)  // 8

// Native clang vector type — accepted by __builtin_nontemporal_store,
// unlike HIP's float4 class.
typedef float f32x4 __attribute__((ext_vector_type(4)));

// ---------------------------------------------------------------------------
// Kernel 1: gather the active diagonal band of weight into workspace.
// w_band[i] = weight[i/3, i]  (flat: (i/3)*INF + i), i in [0, INF)
// ---------------------------------------------------------------------------
__global__ void gather_band_kernel(const float* __restrict__ weight,
                                   float* __restrict__ w_band) {
    int i = blockIdx.x * blockDim.x + threadIdx.x;
    if (i < INF) {
        int row = i / 3;
        w_band[i] = weight[(size_t)row * INF + i];
    }
}

// ---------------------------------------------------------------------------
// Kernel 2: out[b,o] = sum_{j<3} x[b,3o+j] * w_band[3o+j] + bias[o]
// Each thread owns one group r (4 outputs): loads 12 weights + 4 biases into
// REGISTERS once, then loops over 8 batch rows (stride P_SLICES). Inner loop:
// 3 float4 x-loads + 12 FMA + 1 nontemporal float4 store.
// ---------------------------------------------------------------------------
__global__ __launch_bounds__(256)
void banded_matvec_kernel(const float* __restrict__ x,
                          const float* __restrict__ w_band,
                          const float* __restrict__ bias,
                          float* __restrict__ out) {
    int t = blockIdx.x * blockDim.x + threadIdx.x;   // [0, P_SLICES*GROUPS_PER_ROW)
    int p = t / GROUPS_PER_ROW;                      // batch slice
    int r = t - p * GROUPS_PER_ROW;                  // group within row

    // register-resident weights + bias for this group
    const f32x4* wv = reinterpret_cast<const f32x4*>(w_band + (size_t)r * 12);
    f32x4 w0 = wv[0], w1 = wv[1], w2 = wv[2];
    f32x4 bb = *reinterpret_cast<const f32x4*>(bias + (size_t)r * 4);

    const float* xptr = x   + (size_t)p * INF  + (size_t)r * 12;
    float*       optr = out + (size_t)p * OUTF + (size_t)r * 4;

    const size_t x_step = (size_t)P_SLICES * INF;
    const size_t o_step = (size_t)P_SLICES * OUTF;

    #pragma unroll 4
    for (int k = 0; k < ROWS_PER_THREAD; ++k) {
        const f32x4* xv = reinterpret_cast<const f32x4*>(xptr);
        f32x4 x0 = xv[0], x1 = xv[1], x2 = xv[2];

        f32x4 o4;
        o4.x = fmaf(x0.z, w0.z, fmaf(x0.y, w0.y, x0.x * w0.x)) + bb.x;
        o4.y = fmaf(x1.y, w1.y, fmaf(x1.x, w1.x, x0.w * w0.w)) + bb.y;
        o4.z = fmaf(x2.x, w2.x, fmaf(x1.w, w1.w, x1.z * w1.z)) + bb.z;
        o4.w = fmaf(x2.w, w2.w, fmaf(x2.z, w2.z, x2.y * w2.y)) + bb.w;

        __builtin_nontemporal_store(o4, reinterpret_cast<f32x4*>(optr));

        xptr += x_step;
        optr += o_step;
    }
}

extern "C" void kernel_launch(void* const* d_in, const int* in_sizes, int n_in,
                              void* d_out, int out_size, void* d_ws, size_t ws_size,
                              hipStream_t stream) {
    const float* x      = (const float*)d_in[0];   // [B, I]
    const float* weight = (const float*)d_in[1];   // [O, I]
    const float* bias   = (const float*)d_in[2];   // [O]
    float* out          = (float*)d_out;           // [B, O]
    float* w_band       = (float*)d_ws;            // INF floats = 120 KB

    // 1) gather band (30000 elements)
    {
        int threads = 256;
        int blocks = (INF + threads - 1) / threads;
        gather_band_kernel<<<blocks, threads, 0, stream>>>(weight, w_band);
    }

    // 2) main banded reduction: P_SLICES * GROUPS_PER_ROW threads,
    //    each looping over ROWS_PER_THREAD batch rows.
    {
        int total = P_SLICES * GROUPS_PER_ROW;       // 1,280,000
        int threads = 256;
        int blocks = total / threads;                // 5000 exactly
        banded_matvec_kernel<<<blocks, threads, 0, stream>>>(x, w_band, bias, out);
    }
}

// Round 4
// 122.744 us; speedup vs baseline: 1.1147x; 1.1147x over previous
//
#include <hip/hip_runtime.h>

// Problem constants (from reference): B=4096, I=30000, O=10000, I == 3*O.
// Key identity: flat out index o covers flat x floats [3o, 3o+3) with no
// row-boundary breakage (30000 = 12*2500), so the whole op is a flat
// 3:1 banded reduction over B*I floats, with w/bias indices taken mod row.
#define BATCH 4096
#define INF   30000
#define OUTF  10000

#define F4_PER_BLOCK 768            // 3072 floats = 256 output groups per block
#define THREADS      256
#define NBLOCKS      ((BATCH * (INF / 4)) / F4_PER_BLOCK)   // 40000 exactly

typedef float f32x4 __attribute__((ext_vector_type(4)));
typedef float f32x2 __attribute__((ext_vector_type(2)));

// ---------------------------------------------------------------------------
// Kernel 1: gather the active diagonal band of weight into workspace.
// w_band[i] = weight[i/3, i]  (flat: (i/3)*INF + i), i in [0, INF)
// ---------------------------------------------------------------------------
__global__ void gather_band_kernel(const float* __restrict__ weight,
                                   float* __restrict__ w_band) {
    int i = blockIdx.x * blockDim.x + threadIdx.x;
    if (i < INF) {
        int row = i / 3;
        w_band[i] = weight[(size_t)row * INF + i];
    }
}

// ---------------------------------------------------------------------------
// Kernel 2: flat banded reduction, copy-shaped memory access.
// Thread i of block blk loads float4s K = blk*768 + {i, i+256, i+512}
// (16B lane stride — ideal coalescing), reduces each to a partial pair
// (p0,p1) split by phase = K mod 3, stages pairs in LDS, then thread i
// combines P[3i..3i+2] into output float4 G = blk*256 + i (+ bias) and
// stores contiguously.
//   phase 0 (K=3m):   floats->outs 4m,4m,4m,4m+1   : p0=d0+d1+d2, p1=d3
//   phase 1 (K=3m+1): outs 4m+1,4m+1,4m+2,4m+2     : p0=d0+d1,    p1=d2+d3
//   phase 2 (K=3m+2): outs 4m+2,4m+3,4m+3,4m+3     : p0=d0,       p1=d1+d2+d3
//   out[4m]=P[3m].x; out[4m+1]=P[3m].y+P[3m+1].x;
//   out[4m+2]=P[3m+1].y+P[3m+2].x; out[4m+3]=P[3m+2].y
// ---------------------------------------------------------------------------
__global__ __launch_bounds__(THREADS)
void banded_flat_kernel(const float* __restrict__ x,
                        const float* __restrict__ w_band,
                        const float* __restrict__ bias,
                        float* __restrict__ out) {
    __shared__ f32x2 P[F4_PER_BLOCK];   // 6 KB

    const int i = threadIdx.x;
    const unsigned base = (unsigned)blockIdx.x * F4_PER_BLOCK;  // < 30.72M, fits u32

    const f32x4* xv4 = reinterpret_cast<const f32x4*>(x);
    const f32x4* wv4 = reinterpret_cast<const f32x4*>(w_band);  // 7500 float4s

    #pragma unroll
    for (int c = 0; c < 3; ++c) {
        const int k = i + c * THREADS;
        const unsigned K = base + k;

        f32x4 xv = __builtin_nontemporal_load(xv4 + (size_t)K);
        f32x4 wv = wv4[K % 7500u];                 // L2-hot, coalesced

        const float d0 = xv.x * wv.x;
        const float d1 = xv.y * wv.y;
        const float d2 = xv.z * wv.z;
        const float d3 = xv.w * wv.w;

        // phase = K mod 3 = (i + c) mod 3  (768 % 3 == 0, 256 % 3 == 1)
        const int ph = (i + c) % 3;
        f32x2 pr;
        pr.x = d0 + (ph <= 1 ? d1 : 0.f) + (ph == 0 ? d2 : 0.f);
        pr.y = d3 + (ph >= 1 ? d2 : 0.f) + (ph == 2 ? d1 : 0.f);
        P[k] = pr;
    }

    __syncthreads();

    const f32x2 a = P[3 * i];
    const f32x2 b = P[3 * i + 1];
    const f32x2 c2 = P[3 * i + 2];

    const unsigned G = (unsigned)blockIdx.x * THREADS + i;   // output float4 index
    const f32x4 bb = reinterpret_cast<const f32x4*>(bias)[G % 2500u];

    f32x4 o;
    o.x = a.x + bb.x;
    o.y = a.y + b.x + bb.y;
    o.z = b.y + c2.x + bb.z;
    o.w = c2.y + bb.w;

    reinterpret_cast<f32x4*>(out)[(size_t)G] = o;
}

extern "C" void kernel_launch(void* const* d_in, const int* in_sizes, int n_in,
                              void* d_out, int out_size, void* d_ws, size_t ws_size,
                              hipStream_t stream) {
    const float* x      = (const float*)d_in[0];   // [B, I]
    const float* weight = (const float*)d_in[1];   // [O, I]
    const float* bias   = (const float*)d_in[2];   // [O]
    float* out          = (float*)d_out;           // [B, O]
    float* w_band       = (float*)d_ws;            // INF floats = 120 KB

    // 1) gather band (30000 elements)
    {
        int threads = 256;
        int blocks = (INF + threads - 1) / threads;
        gather_band_kernel<<<blocks, threads, 0, stream>>>(weight, w_band);
    }

    // 2) flat banded reduction: 40000 blocks x 256 threads, one-shot
    banded_flat_kernel<<<NBLOCKS, THREADS, 0, stream>>>(x, w_band, bias, out);
}

// Round 5
// 122.494 us; speedup vs baseline: 1.1170x; 1.0020x over previous
//
#include <hip/hip_runtime.h>

// Problem constants: B=4096, I=30000, O=10000, I == 3*O.
// Flat identity: out-flat o covers x-flat [3o,3o+3); rows never break groups
// (30000 = 12*2500). So the op is a flat 3:1 banded reduction over B*I floats
// with w/bias indices periodic (7500 f4 / 2500 f4 per row).
#define BATCH 4096
#define INF   30000
#define OUTF  10000

#define THREADS       256
#define F4_PER_TILE   768
#define TILES_PER_BLK 2
#define F4_PER_BLK    (F4_PER_TILE * TILES_PER_BLK)          // 1536
#define NBLOCKS       ((BATCH * (INF / 4)) / F4_PER_BLK)     // 20000 exactly

typedef float f32x4 __attribute__((ext_vector_type(4)));

// ---------------------------------------------------------------------------
// Kernel 1: gather the active diagonal band of weight into workspace.
// w_band[i] = weight[i/3, i]  (flat: (i/3)*INF + i), i in [0, INF)
// ---------------------------------------------------------------------------
__global__ void gather_band_kernel(const float* __restrict__ weight,
                                   float* __restrict__ w_band) {
    int i = blockIdx.x * blockDim.x + threadIdx.x;
    if (i < INF) {
        int row = i / 3;
        w_band[i] = weight[(size_t)row * INF + i];
    }
}

// ---------------------------------------------------------------------------
// Kernel 2: flat banded reduction, copy-shaped memory access, 2 tiles/block.
// Thread i loads float4s K = blk*1536 + i + 256c, c=0..5 (16B lane stride),
// reduces each to a partial pair split by phase = K mod 3, stages partials
// SoA in LDS (f32, conflict-free both sides), one barrier, then combines
// P[3m..3m+2] into output float4 G = blk*512 + m (+ bias), coalesced store.
//   phase 0: p0=d0+d1+d2, p1=d3
//   phase 1: p0=d0+d1,    p1=d2+d3
//   phase 2: p0=d0,       p1=d1+d2+d3
//   o.x=P0[3m]; o.y=P1[3m]+P0[3m+1]; o.z=P1[3m+1]+P0[3m+2]; o.w=P1[3m+2]
// In-loop modulos replaced by per-block (uniform) mod + add + cond-subtract.
// ---------------------------------------------------------------------------
__global__ __launch_bounds__(THREADS)
void banded_flat_kernel(const float* __restrict__ x,
                        const float* __restrict__ w_band,
                        const float* __restrict__ bias,
                        float* __restrict__ out) {
    __shared__ float P0[F4_PER_BLK];   // 6 KB
    __shared__ float P1[F4_PER_BLK];   // 6 KB

    const int i = threadIdx.x;
    const unsigned b = blockIdx.x;
    const unsigned base = b * (unsigned)F4_PER_BLK;        // f4 index, fits u32
    const unsigned basemod_w = base % 7500u;               // uniform, once
    const unsigned basemod_b = (b * 512u) % 2500u;         // uniform, once

    const f32x4* xv4 = reinterpret_cast<const f32x4*>(x);
    const f32x4* wv4 = reinterpret_cast<const f32x4*>(w_band);   // 7500 f4

    #pragma unroll
    for (int c = 0; c < 6; ++c) {
        const int k = i + c * THREADS;                     // 0..1535
        f32x4 xv = __builtin_nontemporal_load(xv4 + (size_t)(base + k));
        unsigned wi = basemod_w + (unsigned)k;
        if (wi >= 7500u) wi -= 7500u;
        f32x4 wv = wv4[wi];                                // L2-hot, coalesced

        const float d0 = xv.x * wv.x;
        const float d1 = xv.y * wv.y;
        const float d2 = xv.z * wv.z;
        const float d3 = xv.w * wv.w;

        // phase = (base+k) % 3 = k % 3 = (i+c) % 3   (1536%3==0, 256%3==1)
        const int ph = (i + c) % 3;
        P0[k] = d0 + (ph <= 1 ? d1 : 0.f) + (ph == 0 ? d2 : 0.f);
        P1[k] = d3 + (ph >= 1 ? d2 : 0.f) + (ph == 2 ? d1 : 0.f);
    }

    __syncthreads();

    #pragma unroll
    for (int c2 = 0; c2 < 2; ++c2) {
        const int m = i + c2 * THREADS;                    // 0..511
        unsigned bi = basemod_b + (unsigned)m;
        if (bi >= 2500u) bi -= 2500u;
        const f32x4 bb = reinterpret_cast<const f32x4*>(bias)[bi];

        f32x4 o;
        o.x = P0[3*m]               + bb.x;
        o.y = P1[3*m]   + P0[3*m+1] + bb.y;
        o.z = P1[3*m+1] + P0[3*m+2] + bb.z;
        o.w = P1[3*m+2]             + bb.w;

        const unsigned G = b * 512u + (unsigned)m;         // output f4 index
        reinterpret_cast<f32x4*>(out)[(size_t)G] = o;
    }
}

extern "C" void kernel_launch(void* const* d_in, const int* in_sizes, int n_in,
                              void* d_out, int out_size, void* d_ws, size_t ws_size,
                              hipStream_t stream) {
    const float* x      = (const float*)d_in[0];   // [B, I]
    const float* weight = (const float*)d_in[1];   // [O, I]
    const float* bias   = (const float*)d_in[2];   // [O]
    float* out          = (float*)d_out;           // [B, O]
    float* w_band       = (float*)d_ws;            // INF floats = 120 KB

    // 1) gather band (30000 elements)
    {
        int threads = 256;
        int blocks = (INF + threads - 1) / threads;
        gather_band_kernel<<<blocks, threads, 0, stream>>>(weight, w_band);
    }

    // 2) flat banded reduction: 20000 blocks x 256 threads
    banded_flat_kernel<<<NBLOCKS, THREADS, 0, stream>>>(x, w_band, bias, out);
}